// Round 8
// baseline (5738.614 us; speedup 1.0000x reference)
//
#include <hip/hip_runtime.h>

#define Bb 32
#define Tt 512
#define Dd 256
#define Pp 512
#define Hh 512
#define G4 2048
#define TC 128   // time-chunk length (4 chunks)
#define NG 8     // batch groups (4 batches each); gid = blockIdx&7 -> XCD-local
#define WPG 16   // workgroups per group (grid = 128: ONE group per XCD slot)
#define NBG 4    // batches per group

__device__ __forceinline__ float sigmf(float x){ return 1.0f/(1.0f+__expf(-x)); }
__device__ __forceinline__ float tanhf_(float x){ return 1.0f - 2.0f/(__expf(2.0f*x)+1.0f); }

// out[m] = sum_k A[m,k]^2
__global__ void k_rowsq(const float* __restrict__ A, float* __restrict__ o, int M, int K){
  int m = blockIdx.x*blockDim.x + threadIdx.x;
  if (m >= M) return;
  const float4* a4 = (const float4*)(A + (size_t)m*K);
  float s = 0.f;
  for (int i = 0; i < K/4; ++i){ float4 v = a4[i]; s += v.x*v.x + v.y*v.y + v.z*v.z + v.w*v.w; }
  o[m] = s;
}

// out (N x M) = in (M x N)^T
__global__ void k_transpose(const float* __restrict__ in, float* __restrict__ out, int M, int N){
  __shared__ float tile[32][33];
  int bn = blockIdx.x * 32;
  int bm = blockIdx.y * 32;
  int tx = threadIdx.x, ty = threadIdx.y; // block (32,8)
  #pragma unroll
  for (int i = 0; i < 32; i += 8)
    tile[ty+i][tx] = in[(size_t)(bm+ty+i)*N + bn+tx];
  __syncthreads();
  #pragma unroll
  for (int i = 0; i < 32; i += 8)
    out[(size_t)(bn+ty+i)*M + bm+tx] = tile[tx][ty+i];
}

// bx[r] = dot(W_ih[r,:], b_lin) + b_ih[r] + b_hh[r]
__global__ void k_bx(const float* __restrict__ Wih, const float* __restrict__ blin,
                     const float* __restrict__ bih, const float* __restrict__ bhh,
                     float* __restrict__ bx){
  int r = blockIdx.x*blockDim.x + threadIdx.x; // 2048 threads
  const float4* w4 = (const float4*)(Wih + (size_t)r*Hh);
  const float4* b4 = (const float4*)blin;
  float s = 0.f;
  for (int i = 0; i < Hh/4; ++i){ float4 w=w4[i], b=b4[i]; s += w.x*b.x+w.y*b.y+w.z*b.z+w.w*b.w; }
  bx[r] = s + bih[r] + bhh[r];
}

// Generic tiled fp32 GEMM: C[M,N] = epi(A[M,K] @ B[K,N])
// EPI 0: none. EPI 1: exp(-max(rowAux[m]+colAux[n]-2*acc,0)). EPI 2: acc+colAux[n].
// REMAP: A-row (and rowAux) index m -> (m>>7)*Tt + t0 + (m&127); C stays dense.
template<int EPI, bool REMAP>
__global__ __launch_bounds__(256) void k_gemm(const float* __restrict__ A, const float* __restrict__ Bm,
                                              float* __restrict__ C, int M, int N, int K,
                                              const float* __restrict__ rowAux,
                                              const float* __restrict__ colAux, int t0)
{
  __shared__ float As[16][132];
  __shared__ float Bs[16][68];
  const int tid = threadIdx.x;
  const int bm = blockIdx.x * 128;
  const int bn = blockIdx.y * 64;
  const int tm = (tid & 15) * 8;
  const int tn = (tid >> 4) * 4;
  const int arow = tid >> 1;
  const int akq  = (tid & 1) * 8;
  const int brow = tid >> 4;
  const int bcol = (tid & 15) * 4;
  const int am = bm + arow;
  const size_t aRow = REMAP ? ((size_t)(am >> 7) * Tt + t0 + (am & 127)) : (size_t)am;
  float acc[8][4] = {};
  for (int k0 = 0; k0 < K; k0 += 16){
    float4 a0 = *(const float4*)&A[aRow*K + k0 + akq];
    float4 a1 = *(const float4*)&A[aRow*K + k0 + akq + 4];
    float4 bv = *(const float4*)&Bm[(size_t)(k0 + brow)*N + bn + bcol];
    As[akq+0][arow]=a0.x; As[akq+1][arow]=a0.y; As[akq+2][arow]=a0.z; As[akq+3][arow]=a0.w;
    As[akq+4][arow]=a1.x; As[akq+5][arow]=a1.y; As[akq+6][arow]=a1.z; As[akq+7][arow]=a1.w;
    *(float4*)&Bs[brow][bcol] = bv;
    __syncthreads();
    #pragma unroll
    for (int kk = 0; kk < 16; ++kk){
      float4 x0 = *(const float4*)&As[kk][tm];
      float4 x1 = *(const float4*)&As[kk][tm+4];
      float4 y  = *(const float4*)&Bs[kk][tn];
      float av[8] = {x0.x,x0.y,x0.z,x0.w,x1.x,x1.y,x1.z,x1.w};
      #pragma unroll
      for (int i=0;i<8;++i){
        float a = av[i];
        acc[i][0] += a*y.x; acc[i][1] += a*y.y; acc[i][2] += a*y.z; acc[i][3] += a*y.w;
      }
    }
    __syncthreads();
  }
  #pragma unroll
  for (int i=0;i<8;++i){
    int m = bm + tm + i;
    size_t mAux = REMAP ? ((size_t)(m >> 7) * Tt + t0 + (m & 127)) : (size_t)m;
    float4 o;
    float vv[4];
    #pragma unroll
    for (int j=0;j<4;++j){
      int n = bn + tn + j;
      float v = acc[i][j];
      if (EPI==1)      v = __expf(-fmaxf(rowAux[mAux] + colAux[n] - 2.f*v, 0.f));
      else if (EPI==2) v = v + colAux[n];
      vv[j] = v;
    }
    o.x=vv[0]; o.y=vv[1]; o.z=vv[2]; o.w=vv[3];
    *(float4*)&C[(size_t)m*N + bn + tn] = o;
  }
}

// Persistent LSTM over one time-chunk of TC steps.
// Geometry (measured optimum, r2): grid 128 x 512 thr, cooperative.
// Group gid = blockIdx&7 owns batches [4gid,4gid+4); 16 WGs/group.
// wg = blockIdx>>3 owns j in [wg*32, wg*32+32).
// Mapping (r7, better than r2): ks = lane>>2 (16 k-slices of 32),
// jloc = wv*4 + (lane&3); thread holds ALL 4 gate rows of j = wg*32+jloc
// over k-slice [32ks,32ks+32): W[4][32] = 128 regs (pinned). After the
// ks-reduction, ks==0 lanes own all 4 gates of (j, 4 batches) directly.
// Sync (r2, measured fastest): per-group monotonic counter. Producer:
// __syncthreads (drains every wave's vmcnt) then tid0 RELEASE fetch_add.
// Consumer: tid0 ACQUIRE-polls with s_sleep(1) backoff (single lane, low
// coherence-point pressure), then __syncthreads. Counter is monotonic
// across the 4 chunk launches (memset once per kernel_launch, in-graph).
__global__ __launch_bounds__(512) __attribute__((amdgpu_waves_per_eu(2, 2)))
void k_lstm_persist(const float* __restrict__ Whh, const float* __restrict__ xs,
                    float* __restrict__ cbuf, float* __restrict__ out,
                    unsigned* __restrict__ cnt, int t0)
{
  __shared__ float hbuf[NBG][16][36];   // [batch][ks][32+4 pad] ~9.2 KB
  const int tid  = threadIdx.x;
  const int lane = tid & 63;
  const int wv   = tid >> 6;
  const int ks   = lane >> 2;                    // 0..15
  const int jloc = wv*4 + (lane & 3);            // 0..31
  const int gid  = blockIdx.x & 7;
  const int wg   = blockIdx.x >> 3;              // 0..15
  const int j    = wg*32 + jloc;
  const int b0   = gid*NBG;                      // 4 batches of this group

  // ---- load W: all 4 gate rows of j, k-slice [32ks, 32ks+32) ----
  float W[4][32];
  #pragma unroll
  for (int r = 0; r < 4; ++r){
    const float* wr = &Whh[((size_t)(r*Hh + j))*Hh + ks*32];
    #pragma unroll
    for (int c = 0; c < 8; ++c){
      float4 w = *(const float4*)&wr[c*4];
      W[r][c*4+0]=w.x; W[r][c*4+1]=w.y; W[r][c*4+2]=w.z; W[r][c*4+3]=w.w;
    }
  }
  #pragma unroll
  for (int r = 0; r < 4; ++r)
    #pragma unroll
    for (int c = 0; c < 32; ++c)
      asm volatile("" : "+v"(W[r][c]));

  // c-state for (b0..b0+3, j): used on ks==0 lanes only (loaded redundantly)
  float c_st[NBG] = {0.f,0.f,0.f,0.f};
  if (t0 != 0){
    #pragma unroll
    for (int bl = 0; bl < NBG; ++bl)
      c_st[bl] = cbuf[(size_t)(b0+bl)*Hh + j];
  }

  // h-stage identity: 2048 floats over 512 threads (float4 each)
  const int sbl = tid >> 7;            // 0..3 batch-local
  const int skk = (tid & 127) * 4;     // k base
  const int sq  = skk >> 5, sr = skk & 31;

  for (int tl = 0; tl < TC; ++tl){
    const int t = t0 + tl;

    // prefetch xs for this step (gate-owner lanes only; independent of h)
    float xq[4][NBG];
    if (ks == 0){
      #pragma unroll
      for (int bl = 0; bl < NBG; ++bl){
        const size_t rr = ((size_t)(b0+bl)*TC + tl)*G4 + j;
        #pragma unroll
        for (int g = 0; g < 4; ++g)
          xq[g][bl] = xs[rr + g*Hh];
      }
    }

    // ---- wait: all 16 producers of this group finished step t-1 ----
    // (single-lane acquire-poll with s_sleep backoff — r2's measured-fastest)
    if (t > 0){
      if (tid == 0){
        const unsigned tgt = (unsigned)WPG * (unsigned)t;
        while (__hip_atomic_load(&cnt[gid], __ATOMIC_ACQUIRE, __HIP_MEMORY_SCOPE_AGENT) < tgt)
          __builtin_amdgcn_s_sleep(1);
      }
      __syncthreads();
    }

    // ---- stage h(t-1) into LDS ----
    float4 hv = {0.f,0.f,0.f,0.f};
    if (t > 0){
      const float* src = &out[((size_t)(b0 + sbl)*Tt + (t-1))*Hh + skk];
      hv.x = __hip_atomic_load(src+0, __ATOMIC_RELAXED, __HIP_MEMORY_SCOPE_AGENT);
      hv.y = __hip_atomic_load(src+1, __ATOMIC_RELAXED, __HIP_MEMORY_SCOPE_AGENT);
      hv.z = __hip_atomic_load(src+2, __ATOMIC_RELAXED, __HIP_MEMORY_SCOPE_AGENT);
      hv.w = __hip_atomic_load(src+3, __ATOMIC_RELAXED, __HIP_MEMORY_SCOPE_AGENT);
    }
    *(float4*)&hbuf[sbl][sq][sr] = hv;
    __syncthreads();

    // ---- GEMV: 4 gate rows x 32 k x 4 batches = 512 FMA, 32 ds_read_b128 ----
    float acc[4][NBG];
    #pragma unroll
    for (int r=0;r<4;++r)
      #pragma unroll
      for (int bl=0;bl<NBG;++bl) acc[r][bl]=0.f;
    #pragma unroll
    for (int bl = 0; bl < NBG; ++bl){
      const float* hb = &hbuf[bl][ks][0];
      #pragma unroll
      for (int c = 0; c < 8; ++c){
        float4 p = *(const float4*)&hb[c*4];
        #pragma unroll
        for (int r = 0; r < 4; ++r){
          acc[r][bl] = fmaf(W[r][c*4+0],p.x,acc[r][bl]);
          acc[r][bl] = fmaf(W[r][c*4+1],p.y,acc[r][bl]);
          acc[r][bl] = fmaf(W[r][c*4+2],p.z,acc[r][bl]);
          acc[r][bl] = fmaf(W[r][c*4+3],p.w,acc[r][bl]);
        }
      }
    }
    // reduce over ks (lane bits 2..5)
    #pragma unroll
    for (int m = 4; m <= 32; m <<= 1){
      #pragma unroll
      for (int r=0;r<4;++r)
        #pragma unroll
        for (int bl=0;bl<NBG;++bl)
          acc[r][bl] += __shfl_xor(acc[r][bl], m, 64);
    }

    // ---- gates + state update + h store (gate-owner lanes: ks==0) ----
    if (ks == 0){
      #pragma unroll
      for (int bl = 0; bl < NBG; ++bl){
        float gi = sigmf (acc[0][bl] + xq[0][bl]);
        float gf = sigmf (acc[1][bl] + xq[1][bl]);
        float gg = tanhf_(acc[2][bl] + xq[2][bl]);
        float go = sigmf (acc[3][bl] + xq[3][bl]);
        c_st[bl] = gf*c_st[bl] + gi*gg;
        float h = go * tanhf_(c_st[bl]);
        __hip_atomic_store(&out[((size_t)(b0+bl)*Tt + t)*Hh + j], h,
                           __ATOMIC_RELAXED, __HIP_MEMORY_SCOPE_AGENT);
      }
    }
    __syncthreads();   // every wave drains vmcnt -> all h-stores complete

    // ---- publish: RELEASE fetch_add (one RMW per WG per step) ----
    if (tid == 0)
      __hip_atomic_fetch_add(&cnt[gid], 1u, __ATOMIC_RELEASE, __HIP_MEMORY_SCOPE_AGENT);
  }

  if (ks == 0){
    #pragma unroll
    for (int bl = 0; bl < NBG; ++bl)
      cbuf[(size_t)(b0+bl)*Hh + j] = c_st[bl];
  }
}

extern "C" void kernel_launch(void* const* d_in, const int* in_sizes, int n_in,
                              void* d_out, int out_size, void* d_ws, size_t ws_size,
                              hipStream_t stream)
{
  const float* x    = (const float*)d_in[0];
  const float* prot = (const float*)d_in[1];
  const float* Wlin = (const float*)d_in[2];
  const float* blin = (const float*)d_in[3];
  const float* Wih  = (const float*)d_in[4];
  const float* Whh  = (const float*)d_in[5];
  const float* bih  = (const float*)d_in[6];
  const float* bhh  = (const float*)d_in[7];
  float* out = (float*)d_out;
  float* ws  = (float*)d_ws;

  size_t off = 0;
  auto alloc = [&](size_t n)->float*{ float* p = ws + off; off += (n + 15) & ~((size_t)15); return p; };
  float* x2    = alloc((size_t)Bb*Tt);
  float* p2    = alloc(Pp);
  float* pT    = alloc((size_t)Dd*Pp);
  float* bx    = alloc(G4);
  float* Wx    = alloc((size_t)G4*Pp);
  float* WxT   = alloc((size_t)Pp*G4);
  float* cbuf  = alloc((size_t)Bb*Hh);
  float* featsC= alloc((size_t)Bb*TC*Pp);
  float* xsC   = alloc((size_t)Bb*TC*G4);
  unsigned* cnt = (unsigned*)alloc(16);
  // total ~13.6M floats ~ 55 MB

  // ---- setup ----
  k_rowsq<<<dim3((Bb*Tt)/256), dim3(256), 0, stream>>>(x, x2, Bb*Tt, Dd);
  k_rowsq<<<dim3(Pp/256), dim3(256), 0, stream>>>(prot, p2, Pp, Dd);
  k_transpose<<<dim3(Dd/32, Pp/32), dim3(32,8), 0, stream>>>(prot, pT, Pp, Dd);
  k_bx<<<dim3(G4/256), dim3(256), 0, stream>>>(Wih, blin, bih, bhh, bx);
  k_gemm<0,false><<<dim3(G4/128, Pp/64), dim3(256), 0, stream>>>(Wih, Wlin, Wx, G4, Pp, Hh, nullptr, nullptr, 0);
  k_transpose<<<dim3(Pp/32, G4/32), dim3(32,8), 0, stream>>>(Wx, WxT, G4, Pp);
  hipMemsetAsync(cnt, 0, NG*sizeof(unsigned), stream);   // once per launch (in-graph)

  // ---- main: 4 time-chunks of 128 steps ----
  for (int ch = 0; ch < Tt/TC; ++ch){
    int t0 = ch * TC;
    k_gemm<1,true><<<dim3((Bb*TC)/128, Pp/64), dim3(256), 0, stream>>>(
        x, pT, featsC, Bb*TC, Pp, Dd, x2, p2, t0);
    k_gemm<2,false><<<dim3((Bb*TC)/128, G4/64), dim3(256), 0, stream>>>(
        featsC, WxT, xsC, Bb*TC, G4, Pp, nullptr, bx, 0);
    void* args[] = { (void*)&Whh, (void*)&xsC, (void*)&cbuf, (void*)&out, (void*)&cnt, (void*)&t0 };
    hipLaunchCooperativeKernel((void*)k_lstm_persist, dim3(NG*WPG), dim3(512), args, 0, stream);
  }
}

// Round 9
// 3395.032 us; speedup vs baseline: 1.6903x; 1.6903x over previous
//
#include <hip/hip_runtime.h>

#define Bb 32
#define Tt 512
#define Dd 256
#define Pp 512
#define Hh 512
#define G4 2048
#define TC 128   // time-chunk length (4 chunks)
#define NG 8     // batch groups
#define WPG 16   // workgroups per group (grid = 128)
#define NBG 4    // batches per group

__device__ __forceinline__ float sigmf(float x){ return 1.0f/(1.0f+__expf(-x)); }
__device__ __forceinline__ float tanhf_(float x){ return 1.0f - 2.0f/(__expf(2.0f*x)+1.0f); }

typedef __attribute__((ext_vector_type(8))) short v8s;
typedef __attribute__((ext_vector_type(4))) float f32x4;

// out[m] = sum_k A[m,k]^2
__global__ void k_rowsq(const float* __restrict__ A, float* __restrict__ o, int M, int K){
  int m = blockIdx.x*blockDim.x + threadIdx.x;
  if (m >= M) return;
  const float4* a4 = (const float4*)(A + (size_t)m*K);
  float s = 0.f;
  for (int i = 0; i < K/4; ++i){ float4 v = a4[i]; s += v.x*v.x + v.y*v.y + v.z*v.z + v.w*v.w; }
  o[m] = s;
}

// out (N x M) = in (M x N)^T
__global__ void k_transpose(const float* __restrict__ in, float* __restrict__ out, int M, int N){
  __shared__ float tile[32][33];
  int bn = blockIdx.x * 32;
  int bm = blockIdx.y * 32;
  int tx = threadIdx.x, ty = threadIdx.y; // block (32,8)
  #pragma unroll
  for (int i = 0; i < 32; i += 8)
    tile[ty+i][tx] = in[(size_t)(bm+ty+i)*N + bn+tx];
  __syncthreads();
  #pragma unroll
  for (int i = 0; i < 32; i += 8)
    out[(size_t)(bn+ty+i)*M + bm+tx] = tile[tx][ty+i];
}

// bx[r] = dot(W_ih[r,:], b_lin) + b_ih[r] + b_hh[r]
__global__ void k_bx(const float* __restrict__ Wih, const float* __restrict__ blin,
                     const float* __restrict__ bih, const float* __restrict__ bhh,
                     float* __restrict__ bx){
  int r = blockIdx.x*blockDim.x + threadIdx.x; // 2048 threads
  const float4* w4 = (const float4*)(Wih + (size_t)r*Hh);
  const float4* b4 = (const float4*)blin;
  float s = 0.f;
  for (int i = 0; i < Hh/4; ++i){ float4 w=w4[i], b=b4[i]; s += w.x*b.x+w.y*b.y+w.z*b.z+w.w*b.w; }
  bx[r] = s + bih[r] + bhh[r];
}

// fp32 -> bf16 (RNE), 4 elems/thread
__global__ void k_cvt_bf16(const float* __restrict__ in, ushort* __restrict__ out, int n4){
  int i = blockIdx.x*blockDim.x + threadIdx.x;
  if (i >= n4) return;
  float4 v = ((const float4*)in)[i];
  ushort4 o;
  uint u;
  u = __float_as_uint(v.x); u += 0x7FFF + ((u>>16)&1); o.x = (ushort)(u>>16);
  u = __float_as_uint(v.y); u += 0x7FFF + ((u>>16)&1); o.y = (ushort)(u>>16);
  u = __float_as_uint(v.z); u += 0x7FFF + ((u>>16)&1); o.z = (ushort)(u>>16);
  u = __float_as_uint(v.w); u += 0x7FFF + ((u>>16)&1); o.w = (ushort)(u>>16);
  ((ushort4*)out)[i] = o;
}

// Generic tiled fp32 GEMM: C[M,N] = epi(A[M,K] @ B[K,N])
// EPI 0: none. EPI 1: exp(-max(rowAux[m]+colAux[n]-2*acc,0)).
// REMAP: A-row (and rowAux) index m -> (m>>7)*Tt + t0 + (m&127); C stays dense.
template<int EPI, bool REMAP>
__global__ __launch_bounds__(256) void k_gemm(const float* __restrict__ A, const float* __restrict__ Bm,
                                              float* __restrict__ C, int M, int N, int K,
                                              const float* __restrict__ rowAux,
                                              const float* __restrict__ colAux, int t0)
{
  __shared__ float As[16][132];
  __shared__ float Bs[16][68];
  const int tid = threadIdx.x;
  const int bm = blockIdx.x * 128;
  const int bn = blockIdx.y * 64;
  const int tm = (tid & 15) * 8;
  const int tn = (tid >> 4) * 4;
  const int arow = tid >> 1;
  const int akq  = (tid & 1) * 8;
  const int brow = tid >> 4;
  const int bcol = (tid & 15) * 4;
  const int am = bm + arow;
  const size_t aRow = REMAP ? ((size_t)(am >> 7) * Tt + t0 + (am & 127)) : (size_t)am;
  float acc[8][4] = {};
  for (int k0 = 0; k0 < K; k0 += 16){
    float4 a0 = *(const float4*)&A[aRow*K + k0 + akq];
    float4 a1 = *(const float4*)&A[aRow*K + k0 + akq + 4];
    float4 bv = *(const float4*)&Bm[(size_t)(k0 + brow)*N + bn + bcol];
    As[akq+0][arow]=a0.x; As[akq+1][arow]=a0.y; As[akq+2][arow]=a0.z; As[akq+3][arow]=a0.w;
    As[akq+4][arow]=a1.x; As[akq+5][arow]=a1.y; As[akq+6][arow]=a1.z; As[akq+7][arow]=a1.w;
    *(float4*)&Bs[brow][bcol] = bv;
    __syncthreads();
    #pragma unroll
    for (int kk = 0; kk < 16; ++kk){
      float4 x0 = *(const float4*)&As[kk][tm];
      float4 x1 = *(const float4*)&As[kk][tm+4];
      float4 y  = *(const float4*)&Bs[kk][tn];
      float av[8] = {x0.x,x0.y,x0.z,x0.w,x1.x,x1.y,x1.z,x1.w};
      #pragma unroll
      for (int i=0;i<8;++i){
        float a = av[i];
        acc[i][0] += a*y.x; acc[i][1] += a*y.y; acc[i][2] += a*y.z; acc[i][3] += a*y.w;
      }
    }
    __syncthreads();
  }
  #pragma unroll
  for (int i=0;i<8;++i){
    int m = bm + tm + i;
    size_t mAux = REMAP ? ((size_t)(m >> 7) * Tt + t0 + (m & 127)) : (size_t)m;
    float4 o;
    float vv[4];
    #pragma unroll
    for (int j=0;j<4;++j){
      int n = bn + tn + j;
      float v = acc[i][j];
      if (EPI==1) v = __expf(-fmaxf(rowAux[mAux] + colAux[n] - 2.f*v, 0.f));
      vv[j] = v;
    }
    o.x=vv[0]; o.y=vv[1]; o.z=vv[2]; o.w=vv[3];
    *(float4*)&C[(size_t)m*N + bn + tn] = o;
  }
}

// xs = feats(bf16)[M,K] @ Wx(bf16)[N,K]^T + bx[N], fp32 out. MFMA 16x16x32.
// 128x128 tile, 4 waves (2x2), each wave 64x64 = 4x4 fragments. BK=64.
// Both operands staged [row][k] row-major -> contiguous b128 fragment reads.
__global__ __launch_bounds__(256) void k_xs_mfma(
    const ushort* __restrict__ A, const ushort* __restrict__ Bm,
    const float* __restrict__ bx, float* __restrict__ C, int M, int N, int K)
{
  __shared__ ushort As[128][72];
  __shared__ ushort Ws[128][72];
  const int tid  = threadIdx.x;
  const int bm   = blockIdx.x * 128;
  const int bn   = blockIdx.y * 128;
  const int lane = tid & 63;
  const int w    = tid >> 6;
  const int wr   = w >> 1, wc = w & 1;
  const int srow = tid >> 1;
  const int scol = (tid & 1) * 32;
  const int fr   = lane & 15;        // fragment row/col index
  const int fk   = (lane >> 4) * 8;  // fragment k offset

  f32x4 acc[4][4] = {};

  for (int k0 = 0; k0 < K; k0 += 64){
    const ushort* ag = &A [(size_t)(bm + srow)*K + k0 + scol];
    const ushort* wg = &Bm[(size_t)(bn + srow)*K + k0 + scol];
    #pragma unroll
    for (int q = 0; q < 4; ++q){
      *(v8s*)&As[srow][scol + q*8] = *(const v8s*)&ag[q*8];
      *(v8s*)&Ws[srow][scol + q*8] = *(const v8s*)&wg[q*8];
    }
    __syncthreads();
    #pragma unroll
    for (int kk = 0; kk < 64; kk += 32){
      v8s af[4], bf[4];
      #pragma unroll
      for (int mi = 0; mi < 4; ++mi)
        af[mi] = *(const v8s*)&As[wr*64 + mi*16 + fr][kk + fk];
      #pragma unroll
      for (int ni = 0; ni < 4; ++ni)
        bf[ni] = *(const v8s*)&Ws[wc*64 + ni*16 + fr][kk + fk];
      #pragma unroll
      for (int mi = 0; mi < 4; ++mi)
        #pragma unroll
        for (int ni = 0; ni < 4; ++ni)
          acc[mi][ni] = __builtin_amdgcn_mfma_f32_16x16x32_bf16(af[mi], bf[ni], acc[mi][ni], 0, 0, 0);
    }
    __syncthreads();
  }

  const int cr = lane >> 4;  // C row group: row = cr*4 + r, col = fr
  #pragma unroll
  for (int ni = 0; ni < 4; ++ni){
    const int n = bn + wc*64 + ni*16 + fr;
    const float bb = bx[n];
    #pragma unroll
    for (int mi = 0; mi < 4; ++mi){
      #pragma unroll
      for (int r = 0; r < 4; ++r){
        const int m = bm + wr*64 + mi*16 + cr*4 + r;
        C[(size_t)m*N + n] = acc[mi][ni][r] + bb;
      }
    }
  }
}

// ============================================================================
// Persistent LSTM — r2-EXACT artifact (measured 775 us/chunk). DO NOT EDIT.
// Grid: 128 WGs x 512 thr, cooperative. group gid = blockIdx%8 (4 batches),
// wg = blockIdx/8 owns 32 hidden units j in [wg*32, wg*32+32).
// Thread tid = ug*64 + ks*4 + gsel: W_hh rows (gsel*512 + wg*32+ug*4+r), r<4,
// k in [32ks,32ks+32) held in 128 VGPRs. h staged in XOR-swizzled LDS.
// Sync: per-group monotonic counter (release add / acquire spin, agent scope);
// h exchanged through `out` with relaxed agent-scope atomics.
// ============================================================================
__global__ __launch_bounds__(512, 2) void k_lstm_persist(
    const float* __restrict__ Whh, const float* __restrict__ xs,
    float* __restrict__ cbuf, float* __restrict__ out,
    unsigned* __restrict__ cnt, int t0)
{
  __shared__ float hbuf[NBG*Hh];   // 8 KB, swizzled
  const int tid  = threadIdx.x;
  const int gid  = blockIdx.x & 7;
  const int wg   = blockIdx.x >> 3;
  const int gsel = tid & 3;
  const int ks   = (tid >> 2) & 15;
  const int ug   = tid >> 6;
  const int jbase = wg*32 + ug*4;

  // ---- load W slice into registers (once per chunk) ----
  float W[4][32];
  #pragma unroll
  for (int r = 0; r < 4; ++r){
    const float* wrow = &Whh[(size_t)(gsel*Hh + jbase + r)*Hh + ks*32];
    #pragma unroll
    for (int c = 0; c < 8; ++c){
      float4 w = *(const float4*)&wrow[c*4];
      W[r][c*4+0]=w.x; W[r][c*4+1]=w.y; W[r][c*4+2]=w.z; W[r][c*4+3]=w.w;
    }
  }

  // this lane's post-reduction output identity
  const int rr = ks >> 2;
  const int bl = ks & 3;
  const int j  = jbase + rr;
  const int b  = gid*NBG + bl;
  float c_st = (t0 == 0) ? 0.f : cbuf[(size_t)b*Hh + j];

  // h-stage assignment
  const int sbl = tid >> 7;           // batch-local 0..3
  const int skb = (tid & 127) * 4;    // k base
  const int ssw = skb ^ (((skb >> 5) & 7) << 2);

  for (int tl = 0; tl < TC; ++tl){
    const int t = t0 + tl;
    // ---- stage h(t-1) into swizzled LDS ----
    float4 hv = {0.f,0.f,0.f,0.f};
    if (t > 0){
      const float* src = &out[((size_t)(gid*NBG + sbl)*Tt + (t-1))*Hh + skb];
      hv.x = __hip_atomic_load(src+0, __ATOMIC_RELAXED, __HIP_MEMORY_SCOPE_AGENT);
      hv.y = __hip_atomic_load(src+1, __ATOMIC_RELAXED, __HIP_MEMORY_SCOPE_AGENT);
      hv.z = __hip_atomic_load(src+2, __ATOMIC_RELAXED, __HIP_MEMORY_SCOPE_AGENT);
      hv.w = __hip_atomic_load(src+3, __ATOMIC_RELAXED, __HIP_MEMORY_SCOPE_AGENT);
    }
    *(float4*)&hbuf[sbl*Hh + ssw] = hv;
    __syncthreads();

    // ---- GEMV: acc[r][bl] += W[r][k] * h[bl][k] over this thread's k-slice ----
    float acc[4][4];
    #pragma unroll
    for (int r=0;r<4;++r){ acc[r][0]=0.f; acc[r][1]=0.f; acc[r][2]=0.f; acc[r][3]=0.f; }
    #pragma unroll
    for (int blq = 0; blq < 4; ++blq){
      const float* hb = &hbuf[blq*Hh + ks*32];
      #pragma unroll
      for (int c = 0; c < 8; ++c){
        float4 h4 = *(const float4*)&hb[(c*4) ^ ((ks & 7) << 2)];
        #pragma unroll
        for (int r = 0; r < 4; ++r){
          acc[r][blq] = fmaf(W[r][c*4+0], h4.x, acc[r][blq]);
          acc[r][blq] = fmaf(W[r][c*4+1], h4.y, acc[r][blq]);
          acc[r][blq] = fmaf(W[r][c*4+2], h4.z, acc[r][blq]);
          acc[r][blq] = fmaf(W[r][c*4+3], h4.w, acc[r][blq]);
        }
      }
    }

    // ---- in-wave reduction over ks (lane bits 2-5) ----
    #pragma unroll
    for (int m = 4; m <= 32; m <<= 1){
      #pragma unroll
      for (int r=0;r<4;++r){
        #pragma unroll
        for (int q=0;q<4;++q)
          acc[r][q] += __shfl_xor(acc[r][q], m, 64);
      }
    }
    // lane ks takes (r=ks>>2, q=ks&3)
    float g = acc[0][0];
    #pragma unroll
    for (int r=0;r<4;++r){
      #pragma unroll
      for (int q=0;q<4;++q)
        if (ks == r*4+q) g = acc[r][q];
    }

    // ---- add xs, collect 4 gates (consecutive lanes), update c,h ----
    g += xs[((size_t)b*TC + tl)*G4 + gsel*Hh + j];
    const int lbase = (tid & 63) & ~3;
    float gi = __shfl(g, lbase+0, 64);
    float gf = __shfl(g, lbase+1, 64);
    float gg = __shfl(g, lbase+2, 64);
    float go = __shfl(g, lbase+3, 64);
    gi = sigmf(gi); gf = sigmf(gf); gg = tanhf_(gg); go = sigmf(go);
    c_st = gf*c_st + gi*gg;
    float h = go * tanhf_(c_st);
    if (gsel == 0)
      __hip_atomic_store(&out[((size_t)b*Tt + t)*Hh + j], h,
                         __ATOMIC_RELAXED, __HIP_MEMORY_SCOPE_AGENT);
    __syncthreads();   // drains vmcnt: all this WG's h-stores complete

    // ---- group barrier: monotonic counter, target uses global step t ----
    if (tid == 0){
      __hip_atomic_fetch_add(&cnt[gid], 1u, __ATOMIC_RELEASE, __HIP_MEMORY_SCOPE_AGENT);
      const unsigned tgt = (unsigned)WPG * (unsigned)(t + 1);
      while (__hip_atomic_load(&cnt[gid], __ATOMIC_ACQUIRE, __HIP_MEMORY_SCOPE_AGENT) < tgt)
        __builtin_amdgcn_s_sleep(1);
    }
    __syncthreads();
  }
  if (gsel == 0) cbuf[(size_t)b*Hh + j] = c_st;
}

extern "C" void kernel_launch(void* const* d_in, const int* in_sizes, int n_in,
                              void* d_out, int out_size, void* d_ws, size_t ws_size,
                              hipStream_t stream)
{
  const float* x    = (const float*)d_in[0];
  const float* prot = (const float*)d_in[1];
  const float* Wlin = (const float*)d_in[2];
  const float* blin = (const float*)d_in[3];
  const float* Wih  = (const float*)d_in[4];
  const float* Whh  = (const float*)d_in[5];
  const float* bih  = (const float*)d_in[6];
  const float* bhh  = (const float*)d_in[7];
  float* out = (float*)d_out;
  float* ws  = (float*)d_ws;

  size_t off = 0;
  auto alloc = [&](size_t n)->float*{ float* p = ws + off; off += (n + 15) & ~((size_t)15); return p; };
  float* x2     = alloc((size_t)Bb*Tt);        // 16K
  float* p2     = alloc(Pp);                   // 512
  float* pT     = alloc((size_t)Dd*Pp);        // 128K
  float* bx     = alloc(G4);                   // 2K
  float* Wx     = alloc((size_t)G4*Pp);        // 1M fp32
  ushort* WxB   = (ushort*)alloc((size_t)G4*Pp/2);   // 1M bf16 (0.5M floats)
  float* cbuf   = alloc((size_t)Bb*Hh);        // 16K
  float* featsC = alloc((size_t)Bb*TC*Pp);     // 2M fp32
  ushort* featsB= (ushort*)alloc((size_t)Bb*TC*Pp/2); // 2M bf16
  float* xsC    = alloc((size_t)Bb*TC*G4);     // 8M fp32
  unsigned* cnt = (unsigned*)alloc(16);
  // total ~13.3M floats ~ 53 MB

  // ---- setup ----
  k_rowsq<<<dim3((Bb*Tt)/256), dim3(256), 0, stream>>>(x, x2, Bb*Tt, Dd);
  k_rowsq<<<dim3(Pp/256), dim3(256), 0, stream>>>(prot, p2, Pp, Dd);
  k_transpose<<<dim3(Dd/32, Pp/32), dim3(32,8), 0, stream>>>(prot, pT, Pp, Dd);
  k_bx<<<dim3(G4/256), dim3(256), 0, stream>>>(Wih, blin, bih, bhh, bx);
  // Wx[r,p] = sum_h W_ih[r,h] * W_lin[h,p]   (N=2048 rows, K=512 cols layout)
  k_gemm<0,false><<<dim3(G4/128, Pp/64), dim3(256), 0, stream>>>(Wih, Wlin, Wx, G4, Pp, Hh, nullptr, nullptr, 0);
  k_cvt_bf16<<<dim3((G4*Pp/4)/256), dim3(256), 0, stream>>>(Wx, WxB, G4*Pp/4);
  hipMemsetAsync(cnt, 0, NG*sizeof(unsigned), stream);

  // ---- main: 4 time-chunks of 128 steps ----
  for (int ch = 0; ch < Tt/TC; ++ch){
    int t0 = ch * TC;
    // feats chunk (fp32, RBF epilogue), rows m=(b*128+tl) <- x row (b*512+t0+tl)
    k_gemm<1,true><<<dim3((Bb*TC)/128, Pp/64), dim3(256), 0, stream>>>(
        x, pT, featsC, Bb*TC, Pp, Dd, x2, p2, t0);
    k_cvt_bf16<<<dim3((Bb*TC*Pp/4)/256), dim3(256), 0, stream>>>(featsC, featsB, Bb*TC*Pp/4);
    // xs chunk = featsB @ WxB^T + bx  (MFMA bf16, fp32 accumulate)
    k_xs_mfma<<<dim3((Bb*TC)/128, G4/128), dim3(256), 0, stream>>>(
        featsB, WxB, bx, xsC, Bb*TC, G4, Pp);
    void* args[] = { (void*)&Whh, (void*)&xsC, (void*)&cbuf, (void*)&out, (void*)&cnt, (void*)&t0 };
    hipLaunchCooperativeKernel((void*)k_lstm_persist, dim3(NG*WPG), dim3(512), args, 0, stream);
  }
}